// Round 24
// baseline (134.657 us; speedup 1.0000x reference)
//
#include <hip/hip_runtime.h>
#include <hip/hip_bf16.h>

#define EPSF 1e-15f
#define MAXNF 0.99999f

typedef __attribute__((ext_vector_type(8))) short short8v;
typedef __attribute__((ext_vector_type(8))) ushort ushort8v;
typedef __attribute__((ext_vector_type(4))) float f32x4;

__device__ __forceinline__ float wave_sum(float v) {
#pragma unroll
    for (int off = 32; off > 0; off >>= 1) v += __shfl_xor(v, off, 64);
    return v;
}
__device__ __forceinline__ float rcpf(float x) { return __builtin_amdgcn_rcpf(x); }
// x >= 0; series guard avoids (1-e) cancellation at small x (branchy: wave-uniform x)
__device__ __forceinline__ float tanh_g(float x) {
    if (x < 0.03f) return x * (1.f - 0.33333333f * x * x);
    float e = __expf(-2.f * x);
    return (1.f - e) * rcpf(1.f + e);
}
__device__ __forceinline__ float atanh_g(float x) {
    if (x < 0.03f) return x * (1.f + 0.33333333f * x * x);
    return 0.5f * __logf((1.f + x) * rcpf(1.f - x));
}
// branchless variants for lane-divergent inputs
__device__ __forceinline__ float tanh_b(float x) {
    float e = __expf(-2.f * x);
    float tv = (1.f - e) * rcpf(1.f + e);
    float sv = x * (1.f - 0.33333333f * x * x);
    return (x < 0.03f) ? sv : tv;
}
__device__ __forceinline__ float atanh_b(float x) {
    float lv = 0.5f * __logf((1.f + x) * rcpf(1.f - x));
    float sv = x * (1.f + 0.33333333f * x * x);
    return (x < 0.03f) ? sv : lv;
}
__device__ __forceinline__ ushort f2bf(float f) {
    uint32_t u = __float_as_uint(f);
    uint32_t r = (u + 0x7fffu + ((u >> 16) & 1u)) >> 16;
    return (ushort)r;
}
__device__ __forceinline__ float bf2f(ushort u) { return __uint_as_float(((uint32_t)u) << 16); }

// ---------------- K0: prep — W1^T/W2^T bf16, WB25, MB25 (wave/row), gq (wave/dot), c = expmap0(b_vel) ----------------
__global__ __launch_bounds__(256) void k_prep(
    const float* __restrict__ W1, const float* __restrict__ W2,
    const float* __restrict__ W_vel, const float* __restrict__ b_vel,
    const float* __restrict__ W_enc, const float* __restrict__ b_enc,
    ushort* __restrict__ W1t, ushort* __restrict__ W2tp,
    ushort* __restrict__ WB25h, ushort* __restrict__ WB25l,
    ushort* __restrict__ MB25h, ushort* __restrict__ MB25l,
    float* __restrict__ gq,
    float* __restrict__ cvec, float* __restrict__ scp) {
    int bid = blockIdx.x, tid = threadIdx.x;
    if (bid == 0) {
        __shared__ float red[4];
        float v = (tid < 128) ? b_vel[tid] : 0.f;
        float p = wave_sum(v * v);
        if ((tid & 63) == 0) red[tid >> 6] = p;
        __syncthreads();
        float ssq = red[0] + red[1] + red[2] + red[3];
        float nn = sqrtf(fmaxf(ssq, EPSF));
        float th = tanhf(nn);
        if (tid < 128) cvec[tid] = th / nn * v;
        if (tid == 0) scp[0] = th * th;
    } else if (bid <= 128) {
        int idx = (bid - 1) * 256 + tid;      // n*128 + k
        int n = idx >> 7, k = idx & 127;
        W1t[idx] = f2bf(W1[k * 256 + n]);
    } else if (bid <= 160) {
        int idx = (bid - 129) * 256 + tid;    // s*256 + j  (s padded to 32)
        int s = idx >> 8, j = idx & 255;
        W2tp[idx] = (s < 24) ? f2bf(W2[j * 24 + s]) : (ushort)0;
    } else if (bid <= 176) {
        int idx = (bid - 161) * 256 + tid;    // d*32 + s
        int d = idx >> 5, s = idx & 31;
        float val = (s < 24) ? W_enc[s * 128 + d] : (s == 24 ? b_enc[d] : 0.f);
        ushort h = f2bf(val);
        WB25h[idx] = h;
        WB25l[idx] = f2bf(val - bf2f(h));
    } else if (bid <= 327) {
        // gq: one wave per dot product (601 total)
        int o = (bid - 177) * 4 + (tid >> 6);
        int lane = tid & 63;
        if (o < 601) {
            const float* pa; const float* pb;
            if (o < 576)      { pa = W_enc + (o / 24) * 128; pb = W_enc + (o % 24) * 128; }
            else if (o < 600) { pa = W_enc + (o - 576) * 128; pb = b_enc; }
            else              { pa = b_enc; pb = b_enc; }
            float2 a = *(const float2*)(pa + lane * 2);
            float2 c = *(const float2*)(pb + lane * 2);
            float p = wave_sum(a.x * c.x + a.y * c.y);
            if (lane == 0) gq[o] = p;
        }
    } else {
        // MB25: one wave per j-row (128 total); M[j][s] = W_enc[s] . W_vel[j] (s=24: b_enc)
        int j = (bid - 328) * 4 + (tid >> 6);
        int lane = tid & 63;
        float2 wv = *(const float2*)(W_vel + j * 128 + lane * 2);
        for (int s = 0; s < 25; ++s) {
            const float* pa = (s < 24) ? (W_enc + s * 128) : b_enc;
            float2 a = *(const float2*)(pa + lane * 2);
            float p = wave_sum(wv.x * a.x + wv.y * a.y);
            if (lane == 0) {
                ushort h = f2bf(p);
                MB25h[j * 32 + s] = h;
                MB25l[j * 32 + s] = f2bf(p - bf2f(h));
            }
        }
        if (lane >= 25 && lane < 32) { MB25h[j * 32 + lane] = 0; MB25l[j * 32 + lane] = 0; }
    }
}

// ---------------- K1: FUSED stats + Gram encode + vz-GEMM + futures (one block = 32 rows, grid 512) ----------------
// Phase A: stats+normalize; gram-scalar pass (independent n, ILP) then recurrence pass -> Avz.
// Phase B: K=32 MFMA GEMMs -> LDS. Phase C: futures -> tanb. LDS overlaid.
__global__ __launch_bounds__(256) void k_gvf(
    const float* __restrict__ x,
    const float* __restrict__ revin_w, const float* __restrict__ revin_b,
    const float* __restrict__ gq, ushort* __restrict__ Avz,
    const ushort* __restrict__ WB25h, const ushort* __restrict__ WB25l,
    const ushort* __restrict__ MB25h, const ushort* __restrict__ MB25l,
    const float* __restrict__ cvec, const float* __restrict__ scp,
    const float* __restrict__ step_sizes, ushort* __restrict__ tanb,
    float* __restrict__ osc_o, float* __restrict__ osh_o) {
    __shared__ __align__(16) char smem[50688];
    float* xall = (float*)smem;                  // 336*33*4 = 44352
    float* psm  = (float*)(smem + 44352);        // 8*32*4 = 1024
    float* ps2m = (float*)(smem + 45376);        // 1024
    float* scs  = (float*)(smem + 46400);        // 128
    float* shs  = (float*)(smem + 46528);        // 128  (phase-A total 46656)
    float* zs   = (float*)smem;                  // 32*132*4 = 16896 (phase-B overlay)
    float* vsb  = (float*)(smem + 16896);
    float* msb  = (float*)(smem + 33792);        // ends 50688

    int bidx = blockIdx.x;
    int b = bidx >> 2, f0 = (bidx & 3) * 32;
    int tid = threadIdx.x;
    int fi = tid & 31, g = tid >> 5;
    // ---- Phase A: stage raw x + stats ----
    {
        float s = 0.f, s2 = 0.f;
        for (int k = 0; k < 42; ++k) {
            int l = g + 8 * k;
            float v = x[((size_t)b * 336 + l) * 128 + f0 + fi];
            xall[l * 33 + fi] = v;
            s += v; s2 += v * v;
        }
        psm[g * 32 + fi] = s; ps2m[g * 32 + fi] = s2;
    }
    __syncthreads();
    if (tid < 32) {
        float S = 0.f, S2 = 0.f;
#pragma unroll
        for (int h = 0; h < 8; ++h) { S += psm[h * 32 + tid]; S2 += ps2m[h * 32 + tid]; }
        float m = S * (1.f / 336.f);
        float var = S2 * (1.f / 336.f) - m * m;
        float sd = sqrtf(var + 1e-5f);
        int ff = f0 + tid;
        float rw = revin_w[ff], rb = revin_b[ff];
        float sc = rw * rcpf(sd);
        scs[tid] = sc;
        shs[tid] = rb - m * sc;
        float ocv = sd * rcpf(rw);
        osc_o[b * 128 + ff] = ocv;
        osh_o[b * 128 + ff] = m - rb * ocv;
    }
    __syncthreads();
    {
        float sc = scs[fi], sh = shs[fi];
        for (int k = 0; k < 42; ++k) {
            int l = g + 8 * k;
            xall[l * 33 + fi] = xall[l * 33 + fi] * sc + sh;
        }
    }
    int lane = tid & 63, w = tid >> 6;
    int f = w * 8 + (lane >> 3), p = lane & 7;
    int t0 = 3 * p;
    float Greg[3][24], wbr[3];
#pragma unroll
    for (int i = 0; i < 3; ++i) {
#pragma unroll
        for (int s3 = 0; s3 < 24; ++s3) Greg[i][s3] = gq[(t0 + i) * 24 + s3];
        wbr[i] = gq[576 + t0 + i];
    }
    float bb = gq[600];
    __syncthreads();

    // ---- Pass 1: gram scalars for all n (independent iterations -> full ILP) ----
    float pd1a[14], pwa[14], pd2a[14];
    {
        float xp0 = 0.f, xp1 = 0.f, xp2 = 0.f;
#pragma unroll
        for (int n = 0; n < 14; ++n) {
            float g0 = 0.f, g1 = 0.f, g2 = 0.f;
#pragma unroll
            for (int s3 = 0; s3 < 24; ++s3) {
                float xv = xall[(n * 24 + s3) * 33 + f];
                g0 += Greg[0][s3] * xv; g1 += Greg[1][s3] * xv; g2 += Greg[2][s3] * xv;
            }
            float xm0 = xall[(n * 24 + t0) * 33 + f];
            float xm1 = xall[(n * 24 + t0 + 1) * 33 + f];
            float xm2 = xall[(n * 24 + t0 + 2) * 33 + f];
            float pd1 = g0 * xm0 + g1 * xm1 + g2 * xm2;
            float pw  = wbr[0] * xm0 + wbr[1] * xm1 + wbr[2] * xm2;
            float pd2 = g0 * xp0 + g1 * xp1 + g2 * xp2;
#pragma unroll
            for (int off = 1; off < 8; off <<= 1) {
                pd1 += __shfl_xor(pd1, off, 64);
                pd2 += __shfl_xor(pd2, off, 64);
                pw  += __shfl_xor(pw, off, 64);
            }
            pd1a[n] = pd1; pwa[n] = pw; pd2a[n] = pd2;
            xp0 = xm0; xp1 = xm1; xp2 = xm2;
        }
    }
    // ---- Pass 2: recurrence over stored scalars (register-only) ----
    float wsum = 0.f; { float pp = 1.f; for (int k2 = 0; k2 < 13; ++k2) { wsum += pp; pp *= 0.9f; } }
    float wi; { float pp = 1.f; for (int k2 = 0; k2 < 12; ++k2) pp *= 0.9f; wi = pp / (wsum * 13.f); }
    float c[14];
#pragma unroll
    for (int m = 0; m < 14; ++m) c[m] = 0.f;
    float sczp = 0.f, szp = 0.f, pwprev = 0.f;
#pragma unroll
    for (int n = 0; n < 14; ++n) {
        float pd1 = pd1a[n], pw = pwa[n], pd2 = pd2a[n];
        float ssq = pd1 + 2.f * pw + bb;
        float nn = sqrtf(fmaxf(ssq, EPSF));
        float th = tanh_g(nn);
        float scz, sz;
        if (th > MAXNF) { scz = MAXNF * rcpf(nn); sz = MAXNF * MAXNF; }
        else            { scz = th * rcpf(nn);    sz = th * th; }
        if (n > 0) {
            float dotup = pd2 + pwprev + pw + bb;
            float xyp = sczp * scz * dotup;
            float t2 = 1.f - 2.f * xyp;
            float den = fmaxf(t2 + szp * sz, EPSF);
            float rden = rcpf(den);
            float a1 = t2 + sz, a2 = 1.f - szp;
            float usq = (a1 * a1 * szp - 2.f * a1 * a2 * xyp + a2 * a2 * sz) * (rden * rden);
            float un = sqrtf(fmaxf(usq, EPSF));
            float art = atanh_g(fminf(un, 1.f - 1e-7f));
            float fac = fmaxf(a2, EPSF) * art * rcpf(un) * rden * wi;
            c[n - 1] += -fac * a1 * sczp;
            c[n]     +=  fac * a2 * scz;
            wi *= (1.f / 0.9f);
        }
        sczp = scz; szp = sz; pwprev = pw;
    }
    float s_v = 0.f;
#pragma unroll
    for (int m = 0; m < 14; ++m) s_v += c[m];
    float sczL = sczp;   // last segment's scale -> z0 = scz*u_13
    size_t rbase = ((size_t)(b * 128 + f0 + f)) * 128;
#pragma unroll
    for (int q = 0; q < 4; ++q) {
        int u = 4 * p + q;
        float vv, vz;
        if (u < 24) {
            float acc = 0.f;
#pragma unroll
            for (int n = 0; n < 14; ++n) acc += c[n] * xall[(n * 24 + u) * 33 + f];
            vv = acc;
            vz = sczL * xall[(312 + u) * 33 + f];
        } else if (u == 24) { vv = s_v; vz = sczL; }
        else { vv = 0.f; vz = 0.f; }
        ushort vh = f2bf(vv); ushort vl = f2bf(vv - bf2f(vh));
        ushort zh = f2bf(vz); ushort zl = f2bf(vz - bf2f(zh));
        Avz[rbase + u] = vh;
        Avz[rbase + 32 + u] = vl;
        Avz[rbase + 64 + u] = zh;
        Avz[rbase + 96 + u] = zl;
    }
    __syncthreads();   // Avz writes visible block-wide; xall dead -> overlay zs/vs/ms

    // ---- Phase B: K=32 MFMA GEMMs -> LDS ----
    int lrow = lane & 15, lk = lane >> 4;
    int r0 = bidx * 32;
    short8v BWh[2], BWl[2], BMh[2], BMl[2];
#pragma unroll
    for (int dt = 0; dt < 2; ++dt) {
        int d = w * 32 + dt * 16 + lrow;
        BWh[dt] = *(const short8v*)(WB25h + d * 32 + lk * 8);
        BWl[dt] = *(const short8v*)(WB25l + d * 32 + lk * 8);
        BMh[dt] = *(const short8v*)(MB25h + d * 32 + lk * 8);
        BMl[dt] = *(const short8v*)(MB25l + d * 32 + lk * 8);
    }
#pragma unroll
    for (int rg = 0; rg < 2; ++rg) {
        const ushort* ap = Avz + (size_t)(r0 + rg * 16 + lrow) * 128;
        short8v Avh = *(const short8v*)(ap + lk * 8);
        short8v Avl = *(const short8v*)(ap + 32 + lk * 8);
        short8v Azh = *(const short8v*)(ap + 64 + lk * 8);
        short8v Azl = *(const short8v*)(ap + 96 + lk * 8);
#pragma unroll
        for (int dt = 0; dt < 2; ++dt) {
            f32x4 aV = (f32x4)(0.f), aZ = (f32x4)(0.f), aM = (f32x4)(0.f);
            aV = __builtin_amdgcn_mfma_f32_16x16x32_bf16(Avh, BWh[dt], aV, 0, 0, 0);
            aV = __builtin_amdgcn_mfma_f32_16x16x32_bf16(Avh, BWl[dt], aV, 0, 0, 0);
            aV = __builtin_amdgcn_mfma_f32_16x16x32_bf16(Avl, BWh[dt], aV, 0, 0, 0);
            aZ = __builtin_amdgcn_mfma_f32_16x16x32_bf16(Azh, BWh[dt], aZ, 0, 0, 0);
            aZ = __builtin_amdgcn_mfma_f32_16x16x32_bf16(Azh, BWl[dt], aZ, 0, 0, 0);
            aZ = __builtin_amdgcn_mfma_f32_16x16x32_bf16(Azl, BWh[dt], aZ, 0, 0, 0);
            aM = __builtin_amdgcn_mfma_f32_16x16x32_bf16(Avh, BMh[dt], aM, 0, 0, 0);
            aM = __builtin_amdgcn_mfma_f32_16x16x32_bf16(Avh, BMl[dt], aM, 0, 0, 0);
            aM = __builtin_amdgcn_mfma_f32_16x16x32_bf16(Avl, BMh[dt], aM, 0, 0, 0);
            int d = w * 32 + dt * 16 + lrow;
#pragma unroll
            for (int j = 0; j < 4; ++j) {
                int row = rg * 16 + lk * 4 + j;
                vsb[row * 132 + d] = aV[j];
                zs[row * 132 + d] = aZ[j];
                msb[row * 132 + d] = aM[j];
            }
        }
    }
    __syncthreads();
    // ---- Phase C: futures — wave handles rows w*8 .. w*8+7 ----
    float scc = scp[0];
    float step = rcpf(1.f + __expf(-step_sizes[0]));
    float2 cv = *(const float2*)&cvec[lane * 2];
    float tl = (float)((lane & 7) + 1);
    uint* t32 = (uint*)tanb;
    for (int q = 0; q < 8; ++q) {
        int rl = w * 8 + q;
        int r = r0 + rl;
        float2 vi = *(const float2*)&vsb[rl * 132 + lane * 2];
        float2 mx = *(const float2*)&msb[rl * 132 + lane * 2];
        float2 z0 = *(const float2*)&zs[rl * 132 + lane * 2];
        float xn2  = wave_sum(vi.x * vi.x + vi.y * vi.y);
        float mxn2 = wave_sum(mx.x * mx.x + mx.y * mx.y);
        float mxc  = wave_sum(mx.x * cv.x + mx.y * cv.y);
        float z0mx = wave_sum(z0.x * mx.x + z0.y * mx.y);
        float z0c  = wave_sum(z0.x * cv.x + z0.y * cv.y);
        float x2   = wave_sum(z0.x * z0.x + z0.y * z0.y);
        float xn = sqrtf(fmaxf(xn2, EPSF));
        float mxn = sqrtf(fmaxf(mxn2, EPSF));
        float artx = atanh_g(fminf(xn, 1.f - 1e-7f));
        float tm = tanh_g(mxn * rcpf(xn) * artx);
        float scm = tm * rcpf(mxn);
        float sm = tm * tm;
        float xy2 = scm * mxc;
        float den2 = fmaxf(1.f + 2.f * xy2 + sm * scc, EPSF);
        float rd2 = rcpf(den2);
        float A2 = (1.f + 2.f * xy2 + scc) * scm * rd2;
        float B2 = (1.f - sm) * rd2;
        float v0n2 = A2 * A2 * mxn2 + 2.f * A2 * B2 * mxc + B2 * B2 * scc;
        float nv0 = sqrtf(fmaxf(v0n2, EPSF));
        if (nv0 > MAXNF) { float pf = MAXNF * rcpf(nv0); A2 *= pf; B2 *= pf; nv0 = MAXNF; }
        v0n2 = nv0 * nv0;
        float inv_nv0 = rcpf(nv0);
        float zdv = A2 * z0mx + B2 * z0c;
        float v00 = A2 * mx.x + B2 * cv.x, v01 = A2 * mx.y + B2 * cv.y;
        float il = rcpf(fmaxf(1.f - x2, EPSF));
        float nt_ = step * tl * nv0;
        float th = tanh_b(nt_ * il);
        float xy = th * inv_nv0 * zdv;
        float y2 = th * th;
        float den = fmaxf(1.f + 2.f * xy + x2 * y2, EPSF);
        float rd = rcpf(den);
        float A = (1.f + 2.f * xy + y2) * rd;
        float B = (1.f - x2) * th * inv_nv0 * rd;
        float rsq = A * A * x2 + 2.f * A * B * zdv + B * B * v0n2;
        float nr = sqrtf(fmaxf(rsq, EPSF));
        float pf2 = (nr > MAXNF) ? MAXNF * rcpf(nr) : 1.f;
        A *= pf2; B *= pf2; nr = fminf(nr, MAXNF);
        float art = atanh_b(fminf(nr, 1.f - 1e-7f));
        float tf = art * rcpf(nr);
        float FA = tf * A, FB = tf * B;
        int bbv = r >> 7, ff = r & 127;
#pragma unroll
        for (int t = 0; t < 8; ++t) {
            float FAt = __shfl(FA, t);
            float FBt = __shfl(FB, t);
            uint pk = (uint)f2bf(FAt * z0.x + FBt * v00) | ((uint)f2bf(FAt * z0.y + FBt * v01) << 16);
            t32[((size_t)(bbv * 1024 + t * 128 + ff)) * 64 + lane] = pk;
        }
    }
}

// ---------------- K2: head — ONE WAVE per 16-row group (grid 8192 x 64), ZERO barriers ----------------
// Wave owns 16 rows of a tile: GEMM1 streams W1t B-frags (L2) over 16 nt into private LDS h,
// then GEMM2 over its own h rows. No __syncthreads anywhere; lgkmcnt auto-inserted by compiler.
__global__ __launch_bounds__(64) void k_head(
    const ushort* __restrict__ tanb, const ushort* __restrict__ W1t, const float* __restrict__ b1,
    const ushort* __restrict__ W2tp, const float* __restrict__ b2,
    const float* __restrict__ osc_i, const float* __restrict__ osh_i,
    float* __restrict__ out) {
    __shared__ __align__(16) ushort hs[16][264];   // 8.4 KB, wave-private
    int lane = threadIdx.x & 63;
    int lrow = lane & 15, lk = lane >> 4;
    int bid = blockIdx.x;
    int tile = bid >> 2, rg = bid & 3;

    // A-frags: this wave's 16 rows of tan (rows tile*64 + rg*16 + 0..15), K=128
    const ushort* tp = tanb + ((size_t)(tile * 64 + rg * 16 + lrow)) * 128 + lk * 8;
    short8v A[4];
#pragma unroll
    for (int kk = 0; kk < 4; ++kk) A[kk] = *(const short8v*)(tp + kk * 32);

    // GEMM1: 16 nt passes, B streamed from L2 with 1-deep prefetch
    short8v Bc[4];
#pragma unroll
    for (int kk = 0; kk < 4; ++kk)
        Bc[kk] = *(const short8v*)(W1t + (size_t)(0 * 16 + lrow) * 128 + kk * 32 + lk * 8);
    for (int nt = 0; nt < 16; ++nt) {
        short8v Bn[4];
        if (nt + 1 < 16) {
#pragma unroll
            for (int kk = 0; kk < 4; ++kk)
                Bn[kk] = *(const short8v*)(W1t + (size_t)((nt + 1) * 16 + lrow) * 128 + kk * 32 + lk * 8);
        }
        f32x4 acc = (f32x4)(0.f);
#pragma unroll
        for (int kk = 0; kk < 4; ++kk)
            acc = __builtin_amdgcn_mfma_f32_16x16x32_bf16(A[kk], Bc[kk], acc, 0, 0, 0);
        float b1v = b1[nt * 16 + lrow];
#pragma unroll
        for (int j = 0; j < 4; ++j)
            hs[lk * 4 + j][nt * 16 + lrow] = f2bf(fmaxf(acc[j] + b1v, 0.f));
        if (nt + 1 < 16) {
#pragma unroll
            for (int kk = 0; kk < 4; ++kk) Bc[kk] = Bn[kk];
        }
    }
    // GEMM2: this wave's 16 h-rows over full K=256 (compiler inserts lgkmcnt for hs dep)
    f32x4 acc2[2];
    acc2[0] = (f32x4)(0.f); acc2[1] = (f32x4)(0.f);
#pragma unroll
    for (int kk2 = 0; kk2 < 8; ++kk2) {
        short8v Ah = *(const short8v*)&hs[lrow][kk2 * 32 + lk * 8];
#pragma unroll
        for (int nt2 = 0; nt2 < 2; ++nt2) {
            short8v Bv = *(const short8v*)(W2tp + (size_t)(nt2 * 16 + lrow) * 256 + kk2 * 32 + lk * 8);
            acc2[nt2] = __builtin_amdgcn_mfma_f32_16x16x32_bf16(Ah, Bv, acc2[nt2], 0, 0, 0);
        }
    }
    // direct epilogue: acc2[nt2] = 4 consecutive f (rows) of col=nt2*16+lrow -> one f32x4 store
    int bbk = tile >> 4, rem = tile & 15, tt = rem >> 1, fhalf = rem & 1;
    int fr = rg * 16 + lk * 4, f0 = fhalf << 6;
    f32x4 oc = *(const f32x4*)&osc_i[bbk * 128 + f0 + fr];
    f32x4 oh = *(const f32x4*)&osh_i[bbk * 128 + f0 + fr];
    float b2a = (lrow < 24) ? b2[lrow] : 0.f;
    float b2bv = (lrow < 8) ? b2[16 + lrow] : 0.f;
#pragma unroll
    for (int nt2 = 0; nt2 < 2; ++nt2) {
        int col = nt2 * 16 + lrow;
        if (col < 24) {
            float bb2 = (nt2 == 0) ? b2a : b2bv;
            f32x4 v = acc2[nt2];
            v[0] = (v[0] + bb2) * oc[0] + oh[0];
            v[1] = (v[1] + bb2) * oc[1] + oh[1];
            v[2] = (v[2] + bb2) * oc[2] + oh[2];
            v[3] = (v[3] + bb2) * oc[3] + oh[3];
            *(f32x4*)&out[((size_t)bbk * 192 + tt * 24 + col) * 128 + f0 + fr] = v;
        }
    }
}

extern "C" void kernel_launch(void* const* d_in, const int* in_sizes, int n_in,
                              void* d_out, int out_size, void* d_ws, size_t ws_size,
                              hipStream_t stream) {
    (void)in_sizes; (void)n_in; (void)out_size; (void)ws_size;
    const float* x          = (const float*)d_in[0];
    const float* revin_w    = (const float*)d_in[1];
    const float* revin_b    = (const float*)d_in[2];
    const float* W_enc      = (const float*)d_in[3];
    const float* b_enc      = (const float*)d_in[4];
    const float* W_vel      = (const float*)d_in[5];
    const float* b_vel      = (const float*)d_in[6];
    const float* step_sizes = (const float*)d_in[7];
    const float* W1         = (const float*)d_in[8];
    const float* b1         = (const float*)d_in[9];
    const float* W2         = (const float*)d_in[10];
    const float* b2         = (const float*)d_in[11];
    float* out = (float*)d_out;

    float* wsf   = (float*)d_ws;
    float* osc   = wsf;                          // 16384
    float* osh   = osc + 16384;
    float* cvec  = osh + 16384;                  // 128
    float* scp   = cvec + 128;                   // 64 (pad)
    float* gq    = scp + 64;                     // 640 (601 used)
    ushort* W1t   = (ushort*)(gq + 640);         // 32768
    ushort* W2tp  = W1t + 32768;                 // 8192
    ushort* WB25h = W2tp + 8192;                 // 4096
    ushort* WB25l = WB25h + 4096;                // 4096
    ushort* MB25h = WB25l + 4096;                // 4096
    ushort* MB25l = MB25h + 4096;                // 4096
    ushort* Avz   = MB25l + 4096;                // 16384*128 = 2M ushort (4MB)
    ushort* tanb  = Avz + (size_t)16384 * 128;   // 131072*128 bf16 (33.5MB)

    k_prep<<<dim3(360), dim3(256), 0, stream>>>(W1, W2, W_vel, b_vel, W_enc, b_enc,
                                                W1t, W2tp, WB25h, WB25l, MB25h, MB25l,
                                                gq, cvec, scp);
    k_gvf<<<dim3(512), dim3(256), 0, stream>>>(x, revin_w, revin_b, gq, Avz,
                                               WB25h, WB25l, MB25h, MB25l,
                                               cvec, scp, step_sizes, tanb, osc, osh);
    k_head<<<dim3(8192), dim3(64), 0, stream>>>(tanb, W1t, b1, W2tp, b2, osc, osh, out);
}

// Round 25
// 89.956 us; speedup vs baseline: 1.4969x; 1.4969x over previous
//
#include <hip/hip_runtime.h>
#include <hip/hip_bf16.h>

#define EPSF 1e-15f
#define MAXNF 0.99999f

typedef __attribute__((ext_vector_type(8))) short short8v;
typedef __attribute__((ext_vector_type(8))) ushort ushort8v;
typedef __attribute__((ext_vector_type(4))) float f32x4;

__device__ __forceinline__ float wave_sum(float v) {
#pragma unroll
    for (int off = 32; off > 0; off >>= 1) v += __shfl_xor(v, off, 64);
    return v;
}
__device__ __forceinline__ float rcpf(float x) { return __builtin_amdgcn_rcpf(x); }
// x >= 0; series guard avoids (1-e) cancellation at small x (branchy: wave-uniform x)
__device__ __forceinline__ float tanh_g(float x) {
    if (x < 0.03f) return x * (1.f - 0.33333333f * x * x);
    float e = __expf(-2.f * x);
    return (1.f - e) * rcpf(1.f + e);
}
__device__ __forceinline__ float atanh_g(float x) {
    if (x < 0.03f) return x * (1.f + 0.33333333f * x * x);
    return 0.5f * __logf((1.f + x) * rcpf(1.f - x));
}
// branchless variants for lane-divergent inputs
__device__ __forceinline__ float tanh_b(float x) {
    float e = __expf(-2.f * x);
    float tv = (1.f - e) * rcpf(1.f + e);
    float sv = x * (1.f - 0.33333333f * x * x);
    return (x < 0.03f) ? sv : tv;
}
__device__ __forceinline__ float atanh_b(float x) {
    float lv = 0.5f * __logf((1.f + x) * rcpf(1.f - x));
    float sv = x * (1.f + 0.33333333f * x * x);
    return (x < 0.03f) ? sv : lv;
}
__device__ __forceinline__ ushort f2bf(float f) {
    uint32_t u = __float_as_uint(f);
    uint32_t r = (u + 0x7fffu + ((u >> 16) & 1u)) >> 16;
    return (ushort)r;
}
__device__ __forceinline__ float bf2f(ushort u) { return __uint_as_float(((uint32_t)u) << 16); }

// ---------------- K0: prep — W1^T/W2^T bf16, WB25, MB25 (wave/row), gq (wave/dot), c = expmap0(b_vel) ----------------
__global__ __launch_bounds__(256) void k_prep(
    const float* __restrict__ W1, const float* __restrict__ W2,
    const float* __restrict__ W_vel, const float* __restrict__ b_vel,
    const float* __restrict__ W_enc, const float* __restrict__ b_enc,
    ushort* __restrict__ W1t, ushort* __restrict__ W2tp,
    ushort* __restrict__ WB25h, ushort* __restrict__ WB25l,
    ushort* __restrict__ MB25h, ushort* __restrict__ MB25l,
    float* __restrict__ gq,
    float* __restrict__ cvec, float* __restrict__ scp) {
    int bid = blockIdx.x, tid = threadIdx.x;
    if (bid == 0) {
        __shared__ float red[4];
        float v = (tid < 128) ? b_vel[tid] : 0.f;
        float p = wave_sum(v * v);
        if ((tid & 63) == 0) red[tid >> 6] = p;
        __syncthreads();
        float ssq = red[0] + red[1] + red[2] + red[3];
        float nn = sqrtf(fmaxf(ssq, EPSF));
        float th = tanhf(nn);
        if (tid < 128) cvec[tid] = th / nn * v;
        if (tid == 0) scp[0] = th * th;
    } else if (bid <= 128) {
        int idx = (bid - 1) * 256 + tid;      // n*128 + k
        int n = idx >> 7, k = idx & 127;
        W1t[idx] = f2bf(W1[k * 256 + n]);
    } else if (bid <= 160) {
        int idx = (bid - 129) * 256 + tid;    // s*256 + j  (s padded to 32)
        int s = idx >> 8, j = idx & 255;
        W2tp[idx] = (s < 24) ? f2bf(W2[j * 24 + s]) : (ushort)0;
    } else if (bid <= 176) {
        int idx = (bid - 161) * 256 + tid;    // d*32 + s
        int d = idx >> 5, s = idx & 31;
        float val = (s < 24) ? W_enc[s * 128 + d] : (s == 24 ? b_enc[d] : 0.f);
        ushort h = f2bf(val);
        WB25h[idx] = h;
        WB25l[idx] = f2bf(val - bf2f(h));
    } else if (bid <= 327) {
        // gq: one wave per dot product (601 total)
        int o = (bid - 177) * 4 + (tid >> 6);
        int lane = tid & 63;
        if (o < 601) {
            const float* pa; const float* pb;
            if (o < 576)      { pa = W_enc + (o / 24) * 128; pb = W_enc + (o % 24) * 128; }
            else if (o < 600) { pa = W_enc + (o - 576) * 128; pb = b_enc; }
            else              { pa = b_enc; pb = b_enc; }
            float2 a = *(const float2*)(pa + lane * 2);
            float2 c = *(const float2*)(pb + lane * 2);
            float p = wave_sum(a.x * c.x + a.y * c.y);
            if (lane == 0) gq[o] = p;
        }
    } else {
        // MB25: one wave per j-row (128 total); M[j][s] = W_enc[s] . W_vel[j] (s=24: b_enc)
        int j = (bid - 328) * 4 + (tid >> 6);
        int lane = tid & 63;
        float2 wv = *(const float2*)(W_vel + j * 128 + lane * 2);
        for (int s = 0; s < 25; ++s) {
            const float* pa = (s < 24) ? (W_enc + s * 128) : b_enc;
            float2 a = *(const float2*)(pa + lane * 2);
            float p = wave_sum(wv.x * a.x + wv.y * a.y);
            if (lane == 0) {
                ushort h = f2bf(p);
                MB25h[j * 32 + s] = h;
                MB25l[j * 32 + s] = f2bf(p - bf2f(h));
            }
        }
        if (lane >= 25 && lane < 32) { MB25h[j * 32 + lane] = 0; MB25l[j * 32 + lane] = 0; }
    }
}

// ---------------- K1: FUSED stats + Gram encode + vz-GEMM + futures (one block = 32 rows, grid 512) ----------------
// Phase A: stats+normalize; gram-scalar pass (independent n, ILP) then recurrence pass -> Avz.
// Phase B: K=32 MFMA GEMMs -> LDS. Phase C: futures -> tanb. LDS overlaid.
__global__ __launch_bounds__(256) void k_gvf(
    const float* __restrict__ x,
    const float* __restrict__ revin_w, const float* __restrict__ revin_b,
    const float* __restrict__ gq, ushort* __restrict__ Avz,
    const ushort* __restrict__ WB25h, const ushort* __restrict__ WB25l,
    const ushort* __restrict__ MB25h, const ushort* __restrict__ MB25l,
    const float* __restrict__ cvec, const float* __restrict__ scp,
    const float* __restrict__ step_sizes, ushort* __restrict__ tanb,
    float* __restrict__ osc_o, float* __restrict__ osh_o) {
    __shared__ __align__(16) char smem[50688];
    float* xall = (float*)smem;                  // 336*33*4 = 44352
    float* psm  = (float*)(smem + 44352);        // 8*32*4 = 1024
    float* ps2m = (float*)(smem + 45376);        // 1024
    float* scs  = (float*)(smem + 46400);        // 128
    float* shs  = (float*)(smem + 46528);        // 128  (phase-A total 46656)
    float* zs   = (float*)smem;                  // 32*132*4 = 16896 (phase-B overlay)
    float* vsb  = (float*)(smem + 16896);
    float* msb  = (float*)(smem + 33792);        // ends 50688

    int bidx = blockIdx.x;
    int b = bidx >> 2, f0 = (bidx & 3) * 32;
    int tid = threadIdx.x;
    int fi = tid & 31, g = tid >> 5;
    // ---- Phase A: stage raw x + stats ----
    {
        float s = 0.f, s2 = 0.f;
        for (int k = 0; k < 42; ++k) {
            int l = g + 8 * k;
            float v = x[((size_t)b * 336 + l) * 128 + f0 + fi];
            xall[l * 33 + fi] = v;
            s += v; s2 += v * v;
        }
        psm[g * 32 + fi] = s; ps2m[g * 32 + fi] = s2;
    }
    __syncthreads();
    if (tid < 32) {
        float S = 0.f, S2 = 0.f;
#pragma unroll
        for (int h = 0; h < 8; ++h) { S += psm[h * 32 + tid]; S2 += ps2m[h * 32 + tid]; }
        float m = S * (1.f / 336.f);
        float var = S2 * (1.f / 336.f) - m * m;
        float sd = sqrtf(var + 1e-5f);
        int ff = f0 + tid;
        float rw = revin_w[ff], rb = revin_b[ff];
        float sc = rw * rcpf(sd);
        scs[tid] = sc;
        shs[tid] = rb - m * sc;
        float ocv = sd * rcpf(rw);
        osc_o[b * 128 + ff] = ocv;
        osh_o[b * 128 + ff] = m - rb * ocv;
    }
    __syncthreads();
    {
        float sc = scs[fi], sh = shs[fi];
        for (int k = 0; k < 42; ++k) {
            int l = g + 8 * k;
            xall[l * 33 + fi] = xall[l * 33 + fi] * sc + sh;
        }
    }
    int lane = tid & 63, w = tid >> 6;
    int f = w * 8 + (lane >> 3), p = lane & 7;
    int t0 = 3 * p;
    float Greg[3][24], wbr[3];
#pragma unroll
    for (int i = 0; i < 3; ++i) {
#pragma unroll
        for (int s3 = 0; s3 < 24; ++s3) Greg[i][s3] = gq[(t0 + i) * 24 + s3];
        wbr[i] = gq[576 + t0 + i];
    }
    float bb = gq[600];
    __syncthreads();

    // ---- Pass 1: gram scalars for all n (independent iterations -> full ILP) ----
    float pd1a[14], pwa[14], pd2a[14];
    {
        float xp0 = 0.f, xp1 = 0.f, xp2 = 0.f;
#pragma unroll
        for (int n = 0; n < 14; ++n) {
            float g0 = 0.f, g1 = 0.f, g2 = 0.f;
#pragma unroll
            for (int s3 = 0; s3 < 24; ++s3) {
                float xv = xall[(n * 24 + s3) * 33 + f];
                g0 += Greg[0][s3] * xv; g1 += Greg[1][s3] * xv; g2 += Greg[2][s3] * xv;
            }
            float xm0 = xall[(n * 24 + t0) * 33 + f];
            float xm1 = xall[(n * 24 + t0 + 1) * 33 + f];
            float xm2 = xall[(n * 24 + t0 + 2) * 33 + f];
            float pd1 = g0 * xm0 + g1 * xm1 + g2 * xm2;
            float pw  = wbr[0] * xm0 + wbr[1] * xm1 + wbr[2] * xm2;
            float pd2 = g0 * xp0 + g1 * xp1 + g2 * xp2;
#pragma unroll
            for (int off = 1; off < 8; off <<= 1) {
                pd1 += __shfl_xor(pd1, off, 64);
                pd2 += __shfl_xor(pd2, off, 64);
                pw  += __shfl_xor(pw, off, 64);
            }
            pd1a[n] = pd1; pwa[n] = pw; pd2a[n] = pd2;
            xp0 = xm0; xp1 = xm1; xp2 = xm2;
        }
    }
    // ---- Pass 2: recurrence over stored scalars (register-only) ----
    float wsum = 0.f; { float pp = 1.f; for (int k2 = 0; k2 < 13; ++k2) { wsum += pp; pp *= 0.9f; } }
    float wi; { float pp = 1.f; for (int k2 = 0; k2 < 12; ++k2) pp *= 0.9f; wi = pp / (wsum * 13.f); }
    float c[14];
#pragma unroll
    for (int m = 0; m < 14; ++m) c[m] = 0.f;
    float sczp = 0.f, szp = 0.f, pwprev = 0.f;
#pragma unroll
    for (int n = 0; n < 14; ++n) {
        float pd1 = pd1a[n], pw = pwa[n], pd2 = pd2a[n];
        float ssq = pd1 + 2.f * pw + bb;
        float nn = sqrtf(fmaxf(ssq, EPSF));
        float th = tanh_g(nn);
        float scz, sz;
        if (th > MAXNF) { scz = MAXNF * rcpf(nn); sz = MAXNF * MAXNF; }
        else            { scz = th * rcpf(nn);    sz = th * th; }
        if (n > 0) {
            float dotup = pd2 + pwprev + pw + bb;
            float xyp = sczp * scz * dotup;
            float t2 = 1.f - 2.f * xyp;
            float den = fmaxf(t2 + szp * sz, EPSF);
            float rden = rcpf(den);
            float a1 = t2 + sz, a2 = 1.f - szp;
            float usq = (a1 * a1 * szp - 2.f * a1 * a2 * xyp + a2 * a2 * sz) * (rden * rden);
            float un = sqrtf(fmaxf(usq, EPSF));
            float art = atanh_g(fminf(un, 1.f - 1e-7f));
            float fac = fmaxf(a2, EPSF) * art * rcpf(un) * rden * wi;
            c[n - 1] += -fac * a1 * sczp;
            c[n]     +=  fac * a2 * scz;
            wi *= (1.f / 0.9f);
        }
        sczp = scz; szp = sz; pwprev = pw;
    }
    float s_v = 0.f;
#pragma unroll
    for (int m = 0; m < 14; ++m) s_v += c[m];
    float sczL = sczp;   // last segment's scale -> z0 = scz*u_13
    size_t rbase = ((size_t)(b * 128 + f0 + f)) * 128;
#pragma unroll
    for (int q = 0; q < 4; ++q) {
        int u = 4 * p + q;
        float vv, vz;
        if (u < 24) {
            float acc = 0.f;
#pragma unroll
            for (int n = 0; n < 14; ++n) acc += c[n] * xall[(n * 24 + u) * 33 + f];
            vv = acc;
            vz = sczL * xall[(312 + u) * 33 + f];
        } else if (u == 24) { vv = s_v; vz = sczL; }
        else { vv = 0.f; vz = 0.f; }
        ushort vh = f2bf(vv); ushort vl = f2bf(vv - bf2f(vh));
        ushort zh = f2bf(vz); ushort zl = f2bf(vz - bf2f(zh));
        Avz[rbase + u] = vh;
        Avz[rbase + 32 + u] = vl;
        Avz[rbase + 64 + u] = zh;
        Avz[rbase + 96 + u] = zl;
    }
    __syncthreads();   // Avz writes visible block-wide; xall dead -> overlay zs/vs/ms

    // ---- Phase B: K=32 MFMA GEMMs -> LDS ----
    int lrow = lane & 15, lk = lane >> 4;
    int r0 = bidx * 32;
    short8v BWh[2], BWl[2], BMh[2], BMl[2];
#pragma unroll
    for (int dt = 0; dt < 2; ++dt) {
        int d = w * 32 + dt * 16 + lrow;
        BWh[dt] = *(const short8v*)(WB25h + d * 32 + lk * 8);
        BWl[dt] = *(const short8v*)(WB25l + d * 32 + lk * 8);
        BMh[dt] = *(const short8v*)(MB25h + d * 32 + lk * 8);
        BMl[dt] = *(const short8v*)(MB25l + d * 32 + lk * 8);
    }
#pragma unroll
    for (int rg = 0; rg < 2; ++rg) {
        const ushort* ap = Avz + (size_t)(r0 + rg * 16 + lrow) * 128;
        short8v Avh = *(const short8v*)(ap + lk * 8);
        short8v Avl = *(const short8v*)(ap + 32 + lk * 8);
        short8v Azh = *(const short8v*)(ap + 64 + lk * 8);
        short8v Azl = *(const short8v*)(ap + 96 + lk * 8);
#pragma unroll
        for (int dt = 0; dt < 2; ++dt) {
            f32x4 aV = (f32x4)(0.f), aZ = (f32x4)(0.f), aM = (f32x4)(0.f);
            aV = __builtin_amdgcn_mfma_f32_16x16x32_bf16(Avh, BWh[dt], aV, 0, 0, 0);
            aV = __builtin_amdgcn_mfma_f32_16x16x32_bf16(Avh, BWl[dt], aV, 0, 0, 0);
            aV = __builtin_amdgcn_mfma_f32_16x16x32_bf16(Avl, BWh[dt], aV, 0, 0, 0);
            aZ = __builtin_amdgcn_mfma_f32_16x16x32_bf16(Azh, BWh[dt], aZ, 0, 0, 0);
            aZ = __builtin_amdgcn_mfma_f32_16x16x32_bf16(Azh, BWl[dt], aZ, 0, 0, 0);
            aZ = __builtin_amdgcn_mfma_f32_16x16x32_bf16(Azl, BWh[dt], aZ, 0, 0, 0);
            aM = __builtin_amdgcn_mfma_f32_16x16x32_bf16(Avh, BMh[dt], aM, 0, 0, 0);
            aM = __builtin_amdgcn_mfma_f32_16x16x32_bf16(Avh, BMl[dt], aM, 0, 0, 0);
            aM = __builtin_amdgcn_mfma_f32_16x16x32_bf16(Avl, BMh[dt], aM, 0, 0, 0);
            int d = w * 32 + dt * 16 + lrow;
#pragma unroll
            for (int j = 0; j < 4; ++j) {
                int row = rg * 16 + lk * 4 + j;
                vsb[row * 132 + d] = aV[j];
                zs[row * 132 + d] = aZ[j];
                msb[row * 132 + d] = aM[j];
            }
        }
    }
    __syncthreads();
    // ---- Phase C: futures — wave handles rows w*8 .. w*8+7 ----
    float scc = scp[0];
    float step = rcpf(1.f + __expf(-step_sizes[0]));
    float2 cv = *(const float2*)&cvec[lane * 2];
    float tl = (float)((lane & 7) + 1);
    uint* t32 = (uint*)tanb;
    for (int q = 0; q < 8; ++q) {
        int rl = w * 8 + q;
        int r = r0 + rl;
        float2 vi = *(const float2*)&vsb[rl * 132 + lane * 2];
        float2 mx = *(const float2*)&msb[rl * 132 + lane * 2];
        float2 z0 = *(const float2*)&zs[rl * 132 + lane * 2];
        float xn2  = wave_sum(vi.x * vi.x + vi.y * vi.y);
        float mxn2 = wave_sum(mx.x * mx.x + mx.y * mx.y);
        float mxc  = wave_sum(mx.x * cv.x + mx.y * cv.y);
        float z0mx = wave_sum(z0.x * mx.x + z0.y * mx.y);
        float z0c  = wave_sum(z0.x * cv.x + z0.y * cv.y);
        float x2   = wave_sum(z0.x * z0.x + z0.y * z0.y);
        float xn = sqrtf(fmaxf(xn2, EPSF));
        float mxn = sqrtf(fmaxf(mxn2, EPSF));
        float artx = atanh_g(fminf(xn, 1.f - 1e-7f));
        float tm = tanh_g(mxn * rcpf(xn) * artx);
        float scm = tm * rcpf(mxn);
        float sm = tm * tm;
        float xy2 = scm * mxc;
        float den2 = fmaxf(1.f + 2.f * xy2 + sm * scc, EPSF);
        float rd2 = rcpf(den2);
        float A2 = (1.f + 2.f * xy2 + scc) * scm * rd2;
        float B2 = (1.f - sm) * rd2;
        float v0n2 = A2 * A2 * mxn2 + 2.f * A2 * B2 * mxc + B2 * B2 * scc;
        float nv0 = sqrtf(fmaxf(v0n2, EPSF));
        if (nv0 > MAXNF) { float pf = MAXNF * rcpf(nv0); A2 *= pf; B2 *= pf; nv0 = MAXNF; }
        v0n2 = nv0 * nv0;
        float inv_nv0 = rcpf(nv0);
        float zdv = A2 * z0mx + B2 * z0c;
        float v00 = A2 * mx.x + B2 * cv.x, v01 = A2 * mx.y + B2 * cv.y;
        float il = rcpf(fmaxf(1.f - x2, EPSF));
        float nt_ = step * tl * nv0;
        float th = tanh_b(nt_ * il);
        float xy = th * inv_nv0 * zdv;
        float y2 = th * th;
        float den = fmaxf(1.f + 2.f * xy + x2 * y2, EPSF);
        float rd = rcpf(den);
        float A = (1.f + 2.f * xy + y2) * rd;
        float B = (1.f - x2) * th * inv_nv0 * rd;
        float rsq = A * A * x2 + 2.f * A * B * zdv + B * B * v0n2;
        float nr = sqrtf(fmaxf(rsq, EPSF));
        float pf2 = (nr > MAXNF) ? MAXNF * rcpf(nr) : 1.f;
        A *= pf2; B *= pf2; nr = fminf(nr, MAXNF);
        float art = atanh_b(fminf(nr, 1.f - 1e-7f));
        float tf = art * rcpf(nr);
        float FA = tf * A, FB = tf * B;
        int bbv = r >> 7, ff = r & 127;
#pragma unroll
        for (int t = 0; t < 8; ++t) {
            float FAt = __shfl(FA, t);
            float FBt = __shfl(FB, t);
            uint pk = (uint)f2bf(FAt * z0.x + FBt * v00) | ((uint)f2bf(FAt * z0.y + FBt * v01) << 16);
            t32[((size_t)(bbv * 1024 + t * 128 + ff)) * 64 + lane] = pk;
        }
    }
}

// ---------------- K2: head — N-split waves, B-resident, 4-tile loop (grid 512); barrier-safe prefetch ----------------
// Tile = 64 rows = one (b, t, f-half). Wave w owns GEMM1 cols [w*64,w*64+64). Direct-register epilogue.
__global__ __launch_bounds__(256, 2) void k_head(
    const ushort* __restrict__ tanb, const ushort* __restrict__ W1t, const float* __restrict__ b1,
    const ushort* __restrict__ W2tp, const float* __restrict__ b2,
    const float* __restrict__ osc_i, const float* __restrict__ osh_i,
    float* __restrict__ out) {
    __shared__ __align__(16) ushort hs[64][264];   // 33.8 KB
    int tid = threadIdx.x;
    int wid = tid >> 6, lane = tid & 63;
    int lrow = lane & 15, lk = lane >> 4;

    short8v Bw[4][4];
#pragma unroll
    for (int nt = 0; nt < 4; ++nt) {
        const ushort* wp = W1t + (size_t)((wid * 4 + nt) * 16 + lrow) * 128 + lk * 8;
#pragma unroll
        for (int kk = 0; kk < 4; ++kk) Bw[nt][kk] = *(const short8v*)(wp + kk * 32);
    }
    float b1v[4];
#pragma unroll
    for (int nt = 0; nt < 4; ++nt) b1v[nt] = b1[(wid * 4 + nt) * 16 + lrow];
    float b2a = (lrow < 24) ? b2[lrow] : 0.f;
    float b2bv = (lrow < 8) ? b2[16 + lrow] : 0.f;

    int tile0 = blockIdx.x * 4;
    int bbk = tile0 >> 4;
    int fr = wid * 16 + lk * 4;
    f32x4 oc0 = *(const f32x4*)&osc_i[bbk * 128 + fr];
    f32x4 oh0 = *(const f32x4*)&osh_i[bbk * 128 + fr];
    f32x4 oc1 = *(const f32x4*)&osc_i[bbk * 128 + 64 + fr];
    f32x4 oh1 = *(const f32x4*)&osh_i[bbk * 128 + 64 + fr];

    short8v A[4][4];
    {
        const ushort* tp = tanb + ((size_t)tile0 * 64 + lrow) * 128 + lk * 8;
#pragma unroll
        for (int rg = 0; rg < 4; ++rg)
#pragma unroll
            for (int kk = 0; kk < 4; ++kk)
                A[rg][kk] = *(const short8v*)(tp + (size_t)rg * 2048 + kk * 32);
    }
#pragma unroll
    for (int it = 0; it < 4; ++it) {
        int tile = tile0 + it;
        f32x4 acc[4][4];
#pragma unroll
        for (int rg = 0; rg < 4; ++rg)
#pragma unroll
            for (int nt = 0; nt < 4; ++nt) acc[rg][nt] = (f32x4)(0.f);
#pragma unroll
        for (int kk = 0; kk < 4; ++kk)
#pragma unroll
            for (int rg = 0; rg < 4; ++rg)
#pragma unroll
                for (int nt = 0; nt < 4; ++nt)
                    acc[rg][nt] = __builtin_amdgcn_mfma_f32_16x16x32_bf16(A[rg][kk], Bw[nt][kk], acc[rg][nt], 0, 0, 0);
        __syncthreads();   // bar1: no loads pending here (prefetch moved after bar2)
#pragma unroll
        for (int rg = 0; rg < 4; ++rg)
#pragma unroll
            for (int nt = 0; nt < 4; ++nt)
#pragma unroll
                for (int j = 0; j < 4; ++j)
                    hs[rg * 16 + lk * 4 + j][(wid * 4 + nt) * 16 + lrow] =
                        f2bf(fmaxf(acc[rg][nt][j] + b1v[nt], 0.f));
        __syncthreads();   // bar2
        if (it + 1 < 4) {
            const ushort* tp = tanb + ((size_t)(tile + 1) * 64 + lrow) * 128 + lk * 8;
#pragma unroll
            for (int rg = 0; rg < 4; ++rg)
#pragma unroll
                for (int kk = 0; kk < 4; ++kk)
                    A[rg][kk] = *(const short8v*)(tp + (size_t)rg * 2048 + kk * 32);
        }
        f32x4 acc2[2];
        acc2[0] = (f32x4)(0.f); acc2[1] = (f32x4)(0.f);
#pragma unroll
        for (int kk2 = 0; kk2 < 8; ++kk2) {
            short8v Ah = *(const short8v*)&hs[wid * 16 + lrow][kk2 * 32 + lk * 8];
#pragma unroll
            for (int nt2 = 0; nt2 < 2; ++nt2) {
                short8v Bv = *(const short8v*)(W2tp + (size_t)(nt2 * 16 + lrow) * 256 + kk2 * 32 + lk * 8);
                acc2[nt2] = __builtin_amdgcn_mfma_f32_16x16x32_bf16(Ah, Bv, acc2[nt2], 0, 0, 0);
            }
        }
        int rem = tile & 15, tt = rem >> 1, fhalf = rem & 1;
        f32x4 oc = fhalf ? oc1 : oc0;
        f32x4 oh = fhalf ? oh1 : oh0;
        int f0 = fhalf << 6;
#pragma unroll
        for (int nt2 = 0; nt2 < 2; ++nt2) {
            int col = nt2 * 16 + lrow;
            if (col < 24) {
                float bb2 = (nt2 == 0) ? b2a : b2bv;
                f32x4 v = acc2[nt2];
                v[0] = (v[0] + bb2) * oc[0] + oh[0];
                v[1] = (v[1] + bb2) * oc[1] + oh[1];
                v[2] = (v[2] + bb2) * oc[2] + oh[2];
                v[3] = (v[3] + bb2) * oc[3] + oh[3];
                *(f32x4*)&out[((size_t)bbk * 192 + tt * 24 + col) * 128 + f0 + fr] = v;
            }
        }
    }
}

extern "C" void kernel_launch(void* const* d_in, const int* in_sizes, int n_in,
                              void* d_out, int out_size, void* d_ws, size_t ws_size,
                              hipStream_t stream) {
    (void)in_sizes; (void)n_in; (void)out_size; (void)ws_size;
    const float* x          = (const float*)d_in[0];
    const float* revin_w    = (const float*)d_in[1];
    const float* revin_b    = (const float*)d_in[2];
    const float* W_enc      = (const float*)d_in[3];
    const float* b_enc      = (const float*)d_in[4];
    const float* W_vel      = (const float*)d_in[5];
    const float* b_vel      = (const float*)d_in[6];
    const float* step_sizes = (const float*)d_in[7];
    const float* W1         = (const float*)d_in[8];
    const float* b1         = (const float*)d_in[9];
    const float* W2         = (const float*)d_in[10];
    const float* b2         = (const float*)d_in[11];
    float* out = (float*)d_out;

    float* wsf   = (float*)d_ws;
    float* osc   = wsf;                          // 16384
    float* osh   = osc + 16384;
    float* cvec  = osh + 16384;                  // 128
    float* scp   = cvec + 128;                   // 64 (pad)
    float* gq    = scp + 64;                     // 640 (601 used)
    ushort* W1t   = (ushort*)(gq + 640);         // 32768
    ushort* W2tp  = W1t + 32768;                 // 8192
    ushort* WB25h = W2tp + 8192;                 // 4096
    ushort* WB25l = WB25h + 4096;                // 4096
    ushort* MB25h = WB25l + 4096;                // 4096
    ushort* MB25l = MB25h + 4096;                // 4096
    ushort* Avz   = MB25l + 4096;                // 16384*128 = 2M ushort (4MB)
    ushort* tanb  = Avz + (size_t)16384 * 128;   // 131072*128 bf16 (33.5MB)

    k_prep<<<dim3(360), dim3(256), 0, stream>>>(W1, W2, W_vel, b_vel, W_enc, b_enc,
                                                W1t, W2tp, WB25h, WB25l, MB25h, MB25l,
                                                gq, cvec, scp);
    k_gvf<<<dim3(512), dim3(256), 0, stream>>>(x, revin_w, revin_b, gq, Avz,
                                               WB25h, WB25l, MB25h, MB25l,
                                               cvec, scp, step_sizes, tanb, osc, osh);
    k_head<<<dim3(512), dim3(256), 0, stream>>>(tanb, W1t, b1, W2tp, b2, osc, osh, out);
}